// Round 1
// baseline (202.971 us; speedup 1.0000x reference)
//
#include <hip/hip_runtime.h>
#include <stdint.h>

typedef __attribute__((ext_vector_type(8))) short bf16x8;
typedef __attribute__((ext_vector_type(4))) float f32x4;

__device__ __forceinline__ unsigned short bf16_of(float f) {
  union { float f; uint32_t u; } x; x.f = f;
  uint32_t r = x.u + 0x7fffu + ((x.u >> 16) & 1u);
  return (unsigned short)(r >> 16);
}

#define GLD16(gp, lp) __builtin_amdgcn_global_load_lds( \
    (const __attribute__((address_space(1))) uint32_t*)(gp), \
    (__attribute__((address_space(3))) uint32_t*)(lp), 16, 0, 0)

// ---------------- f32 -> bf16 convert (vectorized) ----------------
__global__ void cvt_f32_bf16(const float* __restrict__ src,
                             unsigned short* __restrict__ dst, int n4) {
  int i = blockIdx.x * blockDim.x + threadIdx.x;
  int stride = gridDim.x * blockDim.x;
  for (int j = i; j < n4; j += stride) {
    float4 f = ((const float4*)src)[j];
    union { unsigned short s[4]; uint2 v; } u;
    u.s[0] = bf16_of(f.x); u.s[1] = bf16_of(f.y);
    u.s[2] = bf16_of(f.z); u.s[3] = bf16_of(f.w);
    ((uint2*)dst)[j] = u.v;
  }
}

// ---------------- GEMM: C[M,N] = A[M,K] * B[N,K]^T (+bias) ----------------
// 128x128 tile, BK=64, 4 waves (2x2), 16x16x32 bf16 MFMA, global_load_lds
// with pre-swizzled global source + XOR-swizzled ds_read (rule #21).
template<int BIAS, int OUTF32>
__global__ __launch_bounds__(256, 2)
void gemm_bt(const unsigned short* __restrict__ A,
             const unsigned short* __restrict__ B,
             void* __restrict__ C, const float* __restrict__ bias,
             int N, int K)
{
  __shared__ __align__(1024) unsigned short As[128 * 64];
  __shared__ __align__(1024) unsigned short Bs[128 * 64];
  const int tid = threadIdx.x;
  const int w = tid >> 6, lane = tid & 63;
  const int bm0 = blockIdx.y * 128, bn0 = blockIdx.x * 128;
  const int wm = (w >> 1) * 64, wn = (w & 1) * 64;
  const int srow = lane >> 3;   // row within 8-row chunk
  const int sc8 = lane & 7;     // 16B slot within 128B row

  f32x4 acc[4][4] = {};

  for (int k0 = 0; k0 < K; k0 += 64) {
    #pragma unroll
    for (int i = 0; i < 4; ++i) {
      const int chunk = i * 4 + w;          // 0..15
      const int row = chunk * 8 + srow;     // 0..127
      const int c8 = sc8 ^ (row & 7);       // pre-swizzled source slot
      GLD16(A + (size_t)(bm0 + row) * K + k0 + c8 * 8, (char*)As + chunk * 1024);
      GLD16(B + (size_t)(bn0 + row) * K + k0 + c8 * 8, (char*)Bs + chunk * 1024);
    }
    __syncthreads();
    {
      const int fr = lane & 15, kg = lane >> 4;
      #pragma unroll
      for (int kt = 0; kt < 2; ++kt) {
        bf16x8 av[4], bv[4];
        const int kb = kt * 64 + kg * 16;
        #pragma unroll
        for (int m = 0; m < 4; ++m) {
          const int r = wm + m * 16 + fr;
          av[m] = *(const bf16x8*)((const char*)As + r * 128 + (kb ^ ((r & 7) << 4)));
        }
        #pragma unroll
        for (int n = 0; n < 4; ++n) {
          const int r = wn + n * 16 + fr;
          bv[n] = *(const bf16x8*)((const char*)Bs + r * 128 + (kb ^ ((r & 7) << 4)));
        }
        #pragma unroll
        for (int m = 0; m < 4; ++m)
          #pragma unroll
          for (int n = 0; n < 4; ++n)
            acc[m][n] = __builtin_amdgcn_mfma_f32_16x16x32_bf16(av[m], bv[n], acc[m][n], 0, 0, 0);
      }
    }
    __syncthreads();
  }

  // epilogue: C/D layout col = lane&15, row = (lane>>4)*4 + reg
  const int fr = lane & 15, rg = lane >> 4;
  #pragma unroll
  for (int m = 0; m < 4; ++m) {
    #pragma unroll
    for (int n = 0; n < 4; ++n) {
      #pragma unroll
      for (int r = 0; r < 4; ++r) {
        const int row = bm0 + wm + m * 16 + rg * 4 + r;
        const int col = bn0 + wn + n * 16 + fr;
        float v = acc[m][n][r];
        if (OUTF32) {
          float bb = BIAS ? bias[col] : 0.0f;
          ((float*)C)[(size_t)row * N + col] = v + bb;
        } else {
          ((unsigned short*)C)[(size_t)row * N + col] = bf16_of(v);
        }
      }
    }
  }
}

// ---------------- block-local attention: one (b,h,g) 64x64 block per WG ----
__global__ __launch_bounds__(256, 2)
void attn_block(const unsigned short* __restrict__ qkv,
                unsigned short* __restrict__ o)
{
  __shared__ __align__(1024) unsigned short Qs[64 * 64];
  __shared__ __align__(1024) unsigned short Ks[64 * 64];
  __shared__ __align__(1024) unsigned short Vt[64 * 64];
  __shared__ __align__(1024) unsigned short Ps[64 * 64];
  const int tid = threadIdx.x, w = tid >> 6, lane = tid & 63;
  const int g = blockIdx.x, h = blockIdx.y, b = blockIdx.z;
  const size_t mbase = (size_t)b * 4096 + (size_t)g * 64;
  const unsigned short* qg = qkv + mbase * 3072 + h * 64;
  const unsigned short* kgl = qkv + mbase * 3072 + 1024 + h * 64;
  const unsigned short* vg = qkv + mbase * 3072 + 2048 + h * 64;

  // stage Q, K (swizzled via pre-swizzled global source)
  #pragma unroll
  for (int i = 0; i < 2; ++i) {
    const int chunk = i * 4 + w;              // 0..7
    const int row = chunk * 8 + (lane >> 3);  // 0..63
    const int c8 = (lane & 7) ^ (row & 7);
    GLD16(qg + (size_t)row * 3072 + c8 * 8, (char*)Qs + chunk * 1024);
    GLD16(kgl + (size_t)row * 3072 + c8 * 8, (char*)Ks + chunk * 1024);
  }
  // stage V transposed (Vt[d][n] = V[n][d]), swizzled, via registers
  #pragma unroll
  for (int i = 0; i < 2; ++i) {
    const int c = i * 256 + tid;
    const int n = c >> 3, d0 = (c & 7) * 8;
    bf16x8 v = *(const bf16x8*)(vg + (size_t)n * 3072 + d0);
    #pragma unroll
    for (int j = 0; j < 8; ++j) {
      const int d = d0 + j;
      const int bo = d * 128 + n * 2;
      *(unsigned short*)((char*)Vt + (bo ^ ((d & 7) << 4))) = (unsigned short)v[j];
    }
  }
  __syncthreads();

  const int fr = lane & 15, kg = lane >> 4;
  // S = Q K^T : wave w owns rows [w*16, w*16+16)
  f32x4 s[4] = {};
  #pragma unroll
  for (int kt = 0; kt < 2; ++kt) {
    const int kb = kt * 64 + kg * 16;
    const int rq = w * 16 + fr;
    bf16x8 aq = *(const bf16x8*)((const char*)Qs + rq * 128 + (kb ^ ((rq & 7) << 4)));
    #pragma unroll
    for (int nf = 0; nf < 4; ++nf) {
      const int rk = nf * 16 + fr;
      bf16x8 bk = *(const bf16x8*)((const char*)Ks + rk * 128 + (kb ^ ((rk & 7) << 4)));
      s[nf] = __builtin_amdgcn_mfma_f32_16x16x32_bf16(aq, bk, s[nf], 0, 0, 0);
    }
  }

  // wave-parallel softmax: row m = w*16 + kg*4 + r; cols spread over 16 lanes x 4 frags
  const float scale = 0.125f;  // 1/sqrt(64)
  float inv[4];
  #pragma unroll
  for (int r = 0; r < 4; ++r) {
    float m0 = fmaxf(fmaxf(s[0][r], s[1][r]), fmaxf(s[2][r], s[3][r]));
    #pragma unroll
    for (int d = 1; d < 16; d <<= 1) m0 = fmaxf(m0, __shfl_xor(m0, d));
    float sum = 0.0f;
    #pragma unroll
    for (int nf = 0; nf < 4; ++nf) {
      float p = __expf((s[nf][r] - m0) * scale);
      s[nf][r] = p;
      sum += p;
    }
    #pragma unroll
    for (int d = 1; d < 16; d <<= 1) sum += __shfl_xor(sum, d);
    inv[r] = 1.0f / sum;
  }

  // P -> LDS (bf16, swizzled)
  #pragma unroll
  for (int r = 0; r < 4; ++r) {
    const int m = w * 16 + kg * 4 + r;
    #pragma unroll
    for (int nf = 0; nf < 4; ++nf) {
      const int bo = m * 128 + (nf * 16 + fr) * 2;
      *(unsigned short*)((char*)Ps + (bo ^ ((m & 7) << 4))) = bf16_of(s[nf][r] * inv[r]);
    }
  }
  __syncthreads();

  // O = P V : a from Ps rows, b from Vt rows (Vt[d][n] so k = n)
  f32x4 oa[4] = {};
  #pragma unroll
  for (int kt = 0; kt < 2; ++kt) {
    const int kb = kt * 64 + kg * 16;
    const int rp = w * 16 + fr;
    bf16x8 ap = *(const bf16x8*)((const char*)Ps + rp * 128 + (kb ^ ((rp & 7) << 4)));
    #pragma unroll
    for (int df = 0; df < 4; ++df) {
      const int rv = df * 16 + fr;
      bf16x8 bv = *(const bf16x8*)((const char*)Vt + rv * 128 + (kb ^ ((rv & 7) << 4)));
      oa[df] = __builtin_amdgcn_mfma_f32_16x16x32_bf16(ap, bv, oa[df], 0, 0, 0);
    }
  }
  #pragma unroll
  for (int df = 0; df < 4; ++df) {
    #pragma unroll
    for (int r = 0; r < 4; ++r) {
      const size_t row = mbase + w * 16 + kg * 4 + r;
      const int col = h * 64 + df * 16 + fr;
      o[row * 1024 + col] = bf16_of(oa[df][r]);
    }
  }
}

// ---------------- launch ----------------
extern "C" void kernel_launch(void* const* d_in, const int* in_sizes, int n_in,
                              void* d_out, int out_size, void* d_ws, size_t ws_size,
                              hipStream_t stream) {
  const float* x     = (const float*)d_in[0];
  const float* w_qkv = (const float*)d_in[1];
  const float* w_out = (const float*)d_in[2];
  const float* b_out = (const float*)d_in[3];
  char* ws = (char*)d_ws;
  const size_t SZ_X  = (size_t)16384 * 1024 * 2;
  const size_t SZ_WQ = (size_t)3072 * 1024 * 2;
  const size_t SZ_WO = (size_t)1024 * 1024 * 2;
  unsigned short* xb  = (unsigned short*)ws;
  unsigned short* wqb = (unsigned short*)(ws + SZ_X);
  unsigned short* wob = (unsigned short*)(ws + SZ_X + SZ_WQ);
  unsigned short* qkv = (unsigned short*)(ws + SZ_X + SZ_WQ + SZ_WO);
  unsigned short* ob  = xb;  // alias: x_bf16 dead after GEMM1

  cvt_f32_bf16<<<2048, 256, 0, stream>>>(x, xb, 16384 * 1024 / 4);
  cvt_f32_bf16<<<512, 256, 0, stream>>>(w_qkv, wqb, 3072 * 1024 / 4);
  cvt_f32_bf16<<<256, 256, 0, stream>>>(w_out, wob, 1024 * 1024 / 4);
  // qkv[16384,3072] = x_bf16 @ w_qkv^T
  gemm_bt<0,0><<<dim3(24, 128), 256, 0, stream>>>(xb, wqb, qkv, nullptr, 3072, 1024);
  // block-local attention -> o[16384,1024]
  attn_block<<<dim3(64, 16, 4), 256, 0, stream>>>(qkv, ob);
  // out[16384,1024] = o @ w_out^T + b_out  (fp32)
  gemm_bt<1,1><<<dim3(8, 128), 256, 0, stream>>>(ob, wob, d_out, b_out, 1024, 1024);
}